// Round 8
// baseline (166.237 us; speedup 1.0000x reference)
//
#include <hip/hip_runtime.h>
#include <hip/hip_bf16.h>

typedef __hip_bfloat16 bf16;
#define B16(f) __float2bfloat16(f)

typedef __attribute__((ext_vector_type(8))) short short8;   // MFMA A/B frag (8 bf16)
typedef __attribute__((ext_vector_type(4))) float f32x4;    // MFMA C/D frag

#define P_DIM 4096   // pixel p = t*1024 + h*32 + w ; x flat index = c*4096 + p
#define AS   72      // gemm LDS row stride (shorts)

// ---------------- K1: fused castwT + xnt (independent halves) ---------------
// grid 768: [0,256) weight cast/transpose ; [256,768) xnt with inline s + rms
__global__ __launch_bounds__(256) void k_pre(const float* __restrict__ x,
                                             const float* __restrict__ cond,
                                             const float* __restrict__ norm_w,
                                             const float* __restrict__ qkv_w,
                                             const float* __restrict__ out_w,
                                             bf16* __restrict__ qkvT,
                                             bf16* __restrict__ outT,
                                             bf16* __restrict__ xn){
  __shared__ float sh[64 * 65];     // 16640 B
  __shared__ float s_red[4][64];
  __shared__ float s_sh[64];
  __shared__ float ssv[64];
  int bid = blockIdx.x;
  int tid = threadIdx.x;
  int grp = tid >> 6, lane = tid & 63;

  if (bid < 256){
    // cast+transpose weights to [n][k] bf16 : 0..191 qkv_w, 192..255 out_w
    int b = bid;
    const float* src; bf16* dst; int NW, n0, c0;
    if (b < 192){ src = qkv_w; dst = qkvT; NW = 1536; n0 = (b % 24) * 64; c0 = (b / 24) * 64; }
    else { int bb = b - 192; src = out_w; dst = outT; NW = 512; n0 = (bb & 7) * 64; c0 = (bb >> 3) * 64; }
    for (int i = grp; i < 64; i += 4)
      sh[i * 65 + lane] = src[(c0 + i) * NW + n0 + lane];
    __syncthreads();
    for (int j = grp; j < 64; j += 4)
      dst[(n0 + j) * 512 + c0 + lane] = B16(sh[lane * 65 + j]);
    return;
  }

  // xnt: 512 blocks = 64 p-tiles x 8 c-tiles
  int b = bid - 256;
  int bp = b & 63, bc = b >> 6;
  int p0 = bp * 64, c0 = bc * 64;

  // inline s[c0+lane] = 1 + sum_f cond[f]*norm_w[f][c0+lane]
  {
    float acc = 0.f;
    for (int f = grp * 64; f < grp * 64 + 64; ++f)
      acc = fmaf(cond[f], norm_w[f * 512 + c0 + lane], acc);
    s_red[grp][lane] = acc;
  }
  // inline ss[p0+lane] = sum_c x[c][p0+lane]^2  (full 512 channels)
  {
    float acc = 0.f;
    for (int c = grp * 128; c < grp * 128 + 128; ++c){
      float v = x[c * P_DIM + p0 + lane];
      acc = fmaf(v, v, acc);
    }
    // accumulate via sh region reuse after barrier below
    __syncthreads();
    if (grp == 0) ssv[lane] = acc;
    __syncthreads();
    if (grp == 1) ssv[lane] += acc;
    __syncthreads();
    if (grp == 2) ssv[lane] += acc;
    __syncthreads();
    if (grp == 3) ssv[lane] += acc;
    if (tid < 64)
      s_sh[tid] = s_red[0][tid] + s_red[1][tid] + s_red[2][tid] + s_red[3][tid] + 1.0f;
  }
  __syncthreads();

  for (int i = grp; i < 64; i += 4)
    sh[i * 65 + lane] = x[(c0 + i) * P_DIM + p0 + lane] * s_sh[i];
  __syncthreads();
  for (int j = grp; j < 64; j += 4){
    float rv = rsqrtf(ssv[j] * (1.0f / 512.0f) + 1e-6f);
    xn[(size_t)(p0 + j) * 512 + c0 + lane] = B16(sh[lane * 65 + j] * rv);
  }
}

// ---------------- K2: MFMA GEMM qkv + fused q/k norm + rope -----------------
// block tile 128x64, BK=64, 4 waves. n-tile: 0..7 q heads, 8..15 k heads, 16..23 v.
__global__ __launch_bounds__(256) void k_gemm_qkv(const bf16* __restrict__ Ab,
                                                  const bf16* __restrict__ BTb,
                                                  const float* __restrict__ scale,
                                                  const float* __restrict__ pos,
                                                  bf16* __restrict__ qkv_bf){
  __shared__ unsigned short a_t[128 * AS];
  __shared__ unsigned short b_t[64 * AS];
  const unsigned short* A  = (const unsigned short*)Ab;
  const unsigned short* BT = (const unsigned short*)BTb;
  int m0 = blockIdx.x * 128;
  int by = blockIdx.y;
  int n0 = by * 64;
  int tid = threadIdx.x;
  int w = tid >> 6, l = tid & 63, g = l >> 4, cb = l & 15;

  f32x4 acc[2][4];
#pragma unroll
  for (int mi = 0; mi < 2; ++mi)
#pragma unroll
    for (int nj = 0; nj < 4; ++nj)
#pragma unroll
      for (int r = 0; r < 4; ++r) acc[mi][nj][r] = 0.f;

  for (int kk = 0; kk < 512; kk += 64){
#pragma unroll
    for (int i = 0; i < 4; ++i){
      int sid = tid + i * 256;
      int row = sid >> 3, seg = sid & 7;
      *(uint4*)&a_t[row * AS + seg * 8] = *(const uint4*)&A[(size_t)(m0 + row) * 512 + kk + seg * 8];
    }
#pragma unroll
    for (int i = 0; i < 2; ++i){
      int sid = tid + i * 256;
      int row = sid >> 3, seg = sid & 7;
      *(uint4*)&b_t[row * AS + seg * 8] = *(const uint4*)&BT[(size_t)(n0 + row) * 512 + kk + seg * 8];
    }
    __syncthreads();
#pragma unroll
    for (int kc = 0; kc < 2; ++kc){
      short8 af[2];
#pragma unroll
      for (int mi = 0; mi < 2; ++mi)
        af[mi] = *(const short8*)&a_t[(w * 32 + mi * 16 + cb) * AS + kc * 32 + g * 8];
#pragma unroll
      for (int nj = 0; nj < 4; ++nj){
        short8 bfr = *(const short8*)&b_t[(nj * 16 + cb) * AS + kc * 32 + g * 8];
#pragma unroll
        for (int mi = 0; mi < 2; ++mi)
          acc[mi][nj] = __builtin_amdgcn_mfma_f32_16x16x32_bf16(af[mi], bfr, acc[mi][nj], 0, 0, 0);
      }
    }
    __syncthreads();
  }

  if (by < 16){
    int head = by & 7;
    float sqs = sqrtf(scale[head]);
    int axis = cb >> 3, fi = cb & 7;
    const float LOG_PI = 1.1447298858494002f;
    const float LOG10F = 2.302585092994046f;
    float f = __expf(LOG_PI + (float)(fi * 8 + head) * (LOG10F / 64.0f));
#pragma unroll
    for (int mi = 0; mi < 2; ++mi)
#pragma unroll
      for (int r = 0; r < 4; ++r){
        float ss = 0.f;
#pragma unroll
        for (int nj = 0; nj < 4; ++nj) ss = fmaf(acc[mi][nj][r], acc[mi][nj][r], ss);
#pragma unroll
        for (int off = 1; off < 16; off <<= 1) ss += __shfl_xor(ss, off, 64);
        float fac = sqs * rsqrtf(ss + 1e-6f);
        int rowg = m0 + w * 32 + mi * 16 + g * 4 + r;
        float th = pos[(rowg & 1023) * 2 + axis] * f;
        float ct = __cosf(th), st = __sinf(th);
        float v0 = acc[mi][0][r] * fac, v1 = acc[mi][1][r] * fac;
        acc[mi][0][r] = v0 * ct - v1 * st;
        acc[mi][1][r] = v1 * ct + v0 * st;
        acc[mi][2][r] *= fac;
        acc[mi][3][r] *= fac;
      }
  }

#pragma unroll
  for (int mi = 0; mi < 2; ++mi)
#pragma unroll
    for (int nj = 0; nj < 4; ++nj){
      int col = n0 + nj * 16 + cb;
#pragma unroll
      for (int r = 0; r < 4; ++r){
        int rowg = m0 + w * 32 + mi * 16 + g * 4 + r;
        qkv_bf[(size_t)rowg * 1536 + col] = B16(acc[mi][nj][r]);
      }
    }
}

// ---------------- K3: MFMA neighborhood attention ---------------------------
#define KL_S 80
#define VT_S 232
#define PP_S 232
__global__ __launch_bounds__(256) void k_attn(const bf16* __restrict__ qkv_bfp,
                                              bf16* __restrict__ o_bf){
  __shared__ unsigned short kp[208 * KL_S];     // 33280 B (>= P 64*232=29696 B)
  __shared__ unsigned short vT[64 * VT_S];      // 29696 B
  const unsigned short* qkv = (const unsigned short*)qkv_bfp;

  int bid = blockIdx.x;            // 512 = 64 patches * 8 heads
  int head = bid & 7;
  int patch = bid >> 3;
  int t = patch >> 4;
  int ph = (patch >> 2) & 3, pw = patch & 3;
  int h0 = ph * 8, w0 = pw * 8;
  int rs = min(max(h0 - 3, 0), 18);
  int cs = min(max(w0 - 3, 0), 18);
  int tbase = t << 10;
  int tid = threadIdx.x;
  int cp = tid & 31, pxg = tid >> 5;

  for (int i = 0; i < 26; ++i){
    int px = i * 8 + pxg;
    unsigned val = 0;
    if (px < 196){
      int rr = px / 14, cc = px - rr * 14;
      size_t pn = (size_t)(tbase + (rs + rr) * 32 + (cs + cc));
      val = *(const unsigned*)&qkv[pn * 1536 + 512 + head * 64 + cp * 2];
    }
    *(unsigned*)&kp[px * KL_S + cp * 2] = val;
  }
  for (int i = 0; i < 14; ++i){
    int pp = i * 8 + pxg;
    int px0 = 2 * pp, px1 = px0 + 1;
    unsigned v0 = 0, v1 = 0;
    if (px0 < 196){
      int rr = px0 / 14, cc = px0 - rr * 14;
      size_t pn = (size_t)(tbase + (rs + rr) * 32 + (cs + cc));
      v0 = *(const unsigned*)&qkv[pn * 1536 + 1024 + head * 64 + cp * 2];
    }
    if (px1 < 196){
      int rr = px1 / 14, cc = px1 - rr * 14;
      size_t pn = (size_t)(tbase + (rs + rr) * 32 + (cs + cc));
      v1 = *(const unsigned*)&qkv[pn * 1536 + 1024 + head * 64 + cp * 2];
    }
    unsigned lo = (v0 & 0xffffu) | (v1 << 16);
    unsigned hi = (v0 >> 16) | (v1 & 0xffff0000u);
    *(unsigned*)&vT[(2 * cp) * VT_S + 2 * pp] = lo;
    *(unsigned*)&vT[(2 * cp + 1) * VT_S + 2 * pp] = hi;
  }

  int w = tid >> 6, l = tid & 63;
  int g = l >> 4, cb = l & 15;

  int q_a = w * 16 + cb;
  size_t abase = (size_t)(tbase + (h0 + (q_a >> 3)) * 32 + (w0 + (q_a & 7))) * 1536 + head * 64;
  short8 qa0 = *(const short8*)&qkv[abase + g * 8];
  short8 qa1 = *(const short8*)&qkv[abase + 32 + g * 8];

  __syncthreads();

  f32x4 acc[13];
#pragma unroll
  for (int nt = 0; nt < 13; ++nt)
#pragma unroll
    for (int r = 0; r < 4; ++r) acc[nt][r] = 0.f;
#pragma unroll
  for (int nt = 0; nt < 13; ++nt){
    short8 kb0 = *(const short8*)&kp[(nt * 16 + cb) * KL_S + g * 8];
    short8 kb1 = *(const short8*)&kp[(nt * 16 + cb) * KL_S + 32 + g * 8];
    acc[nt] = __builtin_amdgcn_mfma_f32_16x16x32_bf16(qa0, kb0, acc[nt], 0, 0, 0);
    acc[nt] = __builtin_amdgcn_mfma_f32_16x16x32_bf16(qa1, kb1, acc[nt], 0, 0, 0);
  }
  __syncthreads();

  int wr0[4], wc0[4];
#pragma unroll
  for (int r = 0; r < 4; ++r){
    int q_l = w * 16 + g * 4 + r;
    int hq = h0 + (q_l >> 3), wq = w0 + (q_l & 7);
    wr0[r] = min(max(hq - 3, 0), 25) - rs;
    wc0[r] = min(max(wq - 3, 0), 25) - cs;
  }
  float mx[4] = {-1e30f, -1e30f, -1e30f, -1e30f};
#pragma unroll
  for (int nt = 0; nt < 13; ++nt){
    int kg = nt * 16 + cb;
    int kr = kg / 14, kc = kg - kr * 14;
    bool kvalid = kg < 196;
#pragma unroll
    for (int r = 0; r < 4; ++r){
      bool v = kvalid && ((unsigned)(kr - wr0[r]) < 7u) && ((unsigned)(kc - wc0[r]) < 7u);
      float lg = v ? acc[nt][r] : -1e30f;
      acc[nt][r] = lg;
      mx[r] = fmaxf(mx[r], lg);
    }
  }
#pragma unroll
  for (int off = 1; off < 16; off <<= 1)
#pragma unroll
    for (int r = 0; r < 4; ++r) mx[r] = fmaxf(mx[r], __shfl_xor(mx[r], off, 64));
  float sm[4] = {0.f, 0.f, 0.f, 0.f};
#pragma unroll
  for (int nt = 0; nt < 13; ++nt)
#pragma unroll
    for (int r = 0; r < 4; ++r){
      float e = __expf(acc[nt][r] - mx[r]);
      acc[nt][r] = e;
      sm[r] += e;
    }
#pragma unroll
  for (int off = 1; off < 16; off <<= 1)
#pragma unroll
    for (int r = 0; r < 4; ++r) sm[r] += __shfl_xor(sm[r], off, 64);
  float inv[4];
#pragma unroll
  for (int r = 0; r < 4; ++r) inv[r] = 1.0f / sm[r];

#pragma unroll
  for (int nt = 0; nt < 13; ++nt)
#pragma unroll
    for (int r = 0; r < 4; ++r)
      *reinterpret_cast<bf16*>(&kp[(w * 16 + g * 4 + r) * PP_S + nt * 16 + cb]) = B16(acc[nt][r] * inv[r]);
#pragma unroll
  for (int r = 0; r < 4; ++r)
    kp[(w * 16 + g * 4 + r) * PP_S + 208 + cb] = 0;
  __syncthreads();

  f32x4 acc2[4];
#pragma unroll
  for (int ct = 0; ct < 4; ++ct)
#pragma unroll
    for (int r = 0; r < 4; ++r) acc2[ct][r] = 0.f;
#pragma unroll
  for (int kt = 0; kt < 7; ++kt){
    short8 pa = *(const short8*)&kp[(w * 16 + cb) * PP_S + kt * 32 + g * 8];
#pragma unroll
    for (int ct = 0; ct < 4; ++ct){
      short8 vb = *(const short8*)&vT[(ct * 16 + cb) * VT_S + kt * 32 + g * 8];
      acc2[ct] = __builtin_amdgcn_mfma_f32_16x16x32_bf16(pa, vb, acc2[ct], 0, 0, 0);
    }
  }
#pragma unroll
  for (int ct = 0; ct < 4; ++ct)
#pragma unroll
    for (int r = 0; r < 4; ++r){
      int q_l = w * 16 + g * 4 + r;
      int p = tbase + (h0 + (q_l >> 3)) * 32 + (w0 + (q_l & 7));
      o_bf[(size_t)p * 512 + head * 64 + ct * 16 + cb] = B16(acc2[ct][r]);
    }
}

// ---------------- K4: MFMA GEMM out (128x64, BK=64) + residual/transpose ----
__global__ __launch_bounds__(256) void k_gemm_out(const bf16* __restrict__ Ab,
                                                  const bf16* __restrict__ BTb,
                                                  const float* __restrict__ xres,
                                                  float* __restrict__ out){
  __shared__ unsigned short a_t[128 * AS];
  __shared__ unsigned short b_t[64 * AS];
  __shared__ float tile[64][65];
  const unsigned short* A  = (const unsigned short*)Ab;
  const unsigned short* BT = (const unsigned short*)BTb;
  int m0 = blockIdx.x * 128;   // pixels
  int n0 = blockIdx.y * 64;    // channels
  int tid = threadIdx.x;
  int w = tid >> 6, l = tid & 63, g = l >> 4, cb = l & 15;

  f32x4 acc[2][4];
#pragma unroll
  for (int mi = 0; mi < 2; ++mi)
#pragma unroll
    for (int nj = 0; nj < 4; ++nj)
#pragma unroll
      for (int r = 0; r < 4; ++r) acc[mi][nj][r] = 0.f;

  for (int kk = 0; kk < 512; kk += 64){
#pragma unroll
    for (int i = 0; i < 4; ++i){
      int sid = tid + i * 256;
      int row = sid >> 3, seg = sid & 7;
      *(uint4*)&a_t[row * AS + seg * 8] = *(const uint4*)&A[(size_t)(m0 + row) * 512 + kk + seg * 8];
    }
#pragma unroll
    for (int i = 0; i < 2; ++i){
      int sid = tid + i * 256;
      int row = sid >> 3, seg = sid & 7;
      *(uint4*)&b_t[row * AS + seg * 8] = *(const uint4*)&BT[(size_t)(n0 + row) * 512 + kk + seg * 8];
    }
    __syncthreads();
#pragma unroll
    for (int kc = 0; kc < 2; ++kc){
      short8 af[2];
#pragma unroll
      for (int mi = 0; mi < 2; ++mi)
        af[mi] = *(const short8*)&a_t[(w * 32 + mi * 16 + cb) * AS + kc * 32 + g * 8];
#pragma unroll
      for (int nj = 0; nj < 4; ++nj){
        short8 bfr = *(const short8*)&b_t[(nj * 16 + cb) * AS + kc * 32 + g * 8];
#pragma unroll
        for (int mi = 0; mi < 2; ++mi)
          acc[mi][nj] = __builtin_amdgcn_mfma_f32_16x16x32_bf16(af[mi], bfr, acc[mi][nj], 0, 0, 0);
      }
    }
    __syncthreads();
  }
  int grp = tid >> 6, lane = tid & 63;
#pragma unroll
  for (int hh = 0; hh < 2; ++hh){
    __syncthreads();
    if ((w >> 1) == hh){
#pragma unroll
      for (int mi = 0; mi < 2; ++mi)
#pragma unroll
        for (int nj = 0; nj < 4; ++nj)
#pragma unroll
          for (int r = 0; r < 4; ++r)
            tile[(w & 1) * 32 + mi * 16 + g * 4 + r][nj * 16 + cb] = acc[mi][nj][r];
    }
    __syncthreads();
    for (int j2 = grp; j2 < 64; j2 += 4){
      int c = n0 + j2;
      int p = m0 + hh * 64 + lane;
      out[(size_t)c * P_DIM + p] = tile[lane][j2] + xres[(size_t)c * P_DIM + p];
    }
  }
}

extern "C" void kernel_launch(void* const* d_in, const int* in_sizes, int n_in,
                              void* d_out, int out_size, void* d_ws, size_t ws_size,
                              hipStream_t stream){
  const float* x      = (const float*)d_in[0];
  const float* pos    = (const float*)d_in[1];
  const float* cond   = (const float*)d_in[2];
  const float* norm_w = (const float*)d_in[3];
  const float* qkv_w  = (const float*)d_in[4];
  const float* scale  = (const float*)d_in[5];
  const float* out_w  = (const float*)d_in[6];
  float* out = (float*)d_out;

  char* wp = (char*)d_ws;
  auto alloc = [&](size_t bytes) -> char* {
    char* r = wp;
    wp += (bytes + 255) & ~((size_t)255);
    return r;
  };
  bf16*  xn       = (bf16*) alloc((size_t)4096 * 512 * 2);
  bf16*  qkvT     = (bf16*) alloc((size_t)1536 * 512 * 2);
  bf16*  outT     = (bf16*) alloc((size_t)512 * 512 * 2);
  bf16*  qkv_bf   = (bf16*) alloc((size_t)4096 * 1536 * 2);
  bf16*  o_bf     = (bf16*) alloc((size_t)4096 * 512 * 2);

  k_pre     <<<768,         256, 0, stream>>>(x, cond, norm_w, qkv_w, out_w,
                                              qkvT, outT, xn);
  k_gemm_qkv<<<dim3(32,24), 256, 0, stream>>>(xn, qkvT, scale, pos, qkv_bf);
  k_attn    <<<512,         256, 0, stream>>>(qkv_bf, o_bf);
  k_gemm_out<<<dim3(32,8),  256, 0, stream>>>(o_bf, outT, x, out);
}

// Round 9
// 133.334 us; speedup vs baseline: 1.2468x; 1.2468x over previous
//
#include <hip/hip_runtime.h>
#include <hip/hip_bf16.h>

typedef __hip_bfloat16 bf16;
#define B16(f) __float2bfloat16(f)

typedef __attribute__((ext_vector_type(8))) short short8;   // MFMA A/B frag (8 bf16)
typedef __attribute__((ext_vector_type(4))) float f32x4;    // MFMA C/D frag

#define P_DIM 4096   // pixel p = t*1024 + h*32 + w ; x flat index = c*4096 + p
#define AS   72      // gemm LDS row stride (shorts)

// ---------------- K1: fused pre-pass, 1280 independent blocks ---------------
//  [0,192)    : qkv_w cast/transpose with s[c] folded in (each block computes
//               its own 64-wide s slice: s = 1 + cond @ norm_w)
//  [192,256)  : out_w cast/transpose (no fold)
//  [256,768)  : xt — pure transpose+cast x -> A bf16 [p][c]
//  [768,1280) : rms partial sums rms_part[slice][p]
__global__ __launch_bounds__(256) void k_pre(const float* __restrict__ x,
                                             const float* __restrict__ cond,
                                             const float* __restrict__ norm_w,
                                             const float* __restrict__ qkv_w,
                                             const float* __restrict__ out_w,
                                             bf16* __restrict__ qkvT,
                                             bf16* __restrict__ outT,
                                             bf16* __restrict__ xt,
                                             float* __restrict__ rms_part){
  __shared__ float sh[64 * 65];     // 16640 B
  __shared__ float s_red[4][64];
  __shared__ float s_sh[64];
  int bid = blockIdx.x;
  int tid = threadIdx.x;
  int grp = tid >> 6, lane = tid & 63;

  if (bid < 192){
    // qkvT[n][c] = bf16( qkv_w[c][n] * s[c] )
    int n0 = (bid % 24) * 64, c0 = (bid / 24) * 64;
    float acc = 0.f;
    for (int f = grp * 64; f < grp * 64 + 64; ++f)
      acc = fmaf(cond[f], norm_w[f * 512 + c0 + lane], acc);
    s_red[grp][lane] = acc;
    for (int i = grp; i < 64; i += 4)
      sh[i * 65 + lane] = qkv_w[(c0 + i) * 1536 + n0 + lane];
    __syncthreads();
    if (tid < 64)
      s_sh[tid] = s_red[0][tid] + s_red[1][tid] + s_red[2][tid] + s_red[3][tid] + 1.0f;
    __syncthreads();
    for (int j = grp; j < 64; j += 4)
      qkvT[(n0 + j) * 512 + c0 + lane] = B16(sh[lane * 65 + j] * s_sh[lane]);
  } else if (bid < 256){
    int bb = bid - 192;
    int n0 = (bb & 7) * 64, c0 = (bb >> 3) * 64;
    for (int i = grp; i < 64; i += 4)
      sh[i * 65 + lane] = out_w[(c0 + i) * 512 + n0 + lane];
    __syncthreads();
    for (int j = grp; j < 64; j += 4)
      outT[(n0 + j) * 512 + c0 + lane] = B16(sh[lane * 65 + j]);
  } else if (bid < 768){
    // xt: transpose+cast x[c][p] -> xt[p][c]
    int b = bid - 256;
    int bp = b & 63, bc = b >> 6;
    int p0 = bp * 64, c0 = bc * 64;
    for (int i = grp; i < 64; i += 4)
      sh[i * 65 + lane] = x[(c0 + i) * P_DIM + p0 + lane];
    __syncthreads();
    for (int j = grp; j < 64; j += 4)
      xt[(size_t)(p0 + j) * 512 + c0 + lane] = B16(sh[lane * 65 + j]);
  } else {
    // rms partial sums: 512 blocks = 64 p-tiles x 8 c-slices
    int b = bid - 768;
    int bp = b & 63, bc = b >> 6;
    int co = tid >> 6, pl = tid & 63;
    int p = bp * 64 + pl;
    float acc = 0.f;
    for (int c = bc * 64 + co; c < bc * 64 + 64; c += 4){
      float v = x[c * P_DIM + p];
      acc = fmaf(v, v, acc);
    }
    sh[co * 64 + pl] = acc;
    __syncthreads();
    if (tid < 64)
      rms_part[bc * P_DIM + bp * 64 + tid] = sh[tid] + sh[64 + tid] + sh[128 + tid] + sh[192 + tid];
  }
}

// ---------------- K2: MFMA GEMM qkv + fused q/k norm/rope, v*rms ------------
// block tile 128x64, BK=64, 4 waves. n-tile by: 0..7 q heads, 8..15 k heads,
// 16..23 v. q/k: per-row rms cancels under L2-norm (eps negligible); v: apply
// rms[p] (from partials) in epilogue.
__global__ __launch_bounds__(256) void k_gemm_qkv(const bf16* __restrict__ Ab,
                                                  const bf16* __restrict__ BTb,
                                                  const float* __restrict__ scale,
                                                  const float* __restrict__ pos,
                                                  const float* __restrict__ rms_part,
                                                  bf16* __restrict__ qkv_bf){
  __shared__ unsigned short a_t[128 * AS];
  __shared__ unsigned short b_t[64 * AS];
  const unsigned short* A  = (const unsigned short*)Ab;
  const unsigned short* BT = (const unsigned short*)BTb;
  int m0 = blockIdx.x * 128;
  int by = blockIdx.y;
  int n0 = by * 64;
  int tid = threadIdx.x;
  int w = tid >> 6, l = tid & 63, g = l >> 4, cb = l & 15;

  f32x4 acc[2][4];
#pragma unroll
  for (int mi = 0; mi < 2; ++mi)
#pragma unroll
    for (int nj = 0; nj < 4; ++nj)
#pragma unroll
      for (int r = 0; r < 4; ++r) acc[mi][nj][r] = 0.f;

  for (int kk = 0; kk < 512; kk += 64){
#pragma unroll
    for (int i = 0; i < 4; ++i){
      int sid = tid + i * 256;
      int row = sid >> 3, seg = sid & 7;
      *(uint4*)&a_t[row * AS + seg * 8] = *(const uint4*)&A[(size_t)(m0 + row) * 512 + kk + seg * 8];
    }
#pragma unroll
    for (int i = 0; i < 2; ++i){
      int sid = tid + i * 256;
      int row = sid >> 3, seg = sid & 7;
      *(uint4*)&b_t[row * AS + seg * 8] = *(const uint4*)&BT[(size_t)(n0 + row) * 512 + kk + seg * 8];
    }
    __syncthreads();
#pragma unroll
    for (int kc = 0; kc < 2; ++kc){
      short8 af[2];
#pragma unroll
      for (int mi = 0; mi < 2; ++mi)
        af[mi] = *(const short8*)&a_t[(w * 32 + mi * 16 + cb) * AS + kc * 32 + g * 8];
#pragma unroll
      for (int nj = 0; nj < 4; ++nj){
        short8 bfr = *(const short8*)&b_t[(nj * 16 + cb) * AS + kc * 32 + g * 8];
#pragma unroll
        for (int mi = 0; mi < 2; ++mi)
          acc[mi][nj] = __builtin_amdgcn_mfma_f32_16x16x32_bf16(af[mi], bfr, acc[mi][nj], 0, 0, 0);
      }
    }
    __syncthreads();
  }

  if (by < 16){
    // q/k: L2-normalize * sqrt(scale[head]) + rope (rms[p] cancels here)
    int head = by & 7;
    float sqs = sqrtf(scale[head]);
    int axis = cb >> 3, fi = cb & 7;
    const float LOG_PI = 1.1447298858494002f;
    const float LOG10F = 2.302585092994046f;
    float f = __expf(LOG_PI + (float)(fi * 8 + head) * (LOG10F / 64.0f));
#pragma unroll
    for (int mi = 0; mi < 2; ++mi)
#pragma unroll
      for (int r = 0; r < 4; ++r){
        float ss = 0.f;
#pragma unroll
        for (int nj = 0; nj < 4; ++nj) ss = fmaf(acc[mi][nj][r], acc[mi][nj][r], ss);
#pragma unroll
        for (int off = 1; off < 16; off <<= 1) ss += __shfl_xor(ss, off, 64);
        float fac = sqs * rsqrtf(ss + 1e-6f);
        int rowg = m0 + w * 32 + mi * 16 + g * 4 + r;
        float th = pos[(rowg & 1023) * 2 + axis] * f;
        float ct = __cosf(th), st = __sinf(th);
        float v0 = acc[mi][0][r] * fac, v1 = acc[mi][1][r] * fac;
        acc[mi][0][r] = v0 * ct - v1 * st;
        acc[mi][1][r] = v1 * ct + v0 * st;
        acc[mi][2][r] *= fac;
        acc[mi][3][r] *= fac;
      }
  } else {
    // v: scale each row by rms[p] = rsqrt(mean_c x^2 + eps)
#pragma unroll
    for (int mi = 0; mi < 2; ++mi)
#pragma unroll
      for (int r = 0; r < 4; ++r){
        int rowg = m0 + w * 32 + mi * 16 + g * 4 + r;
        float ss = 0.f;
#pragma unroll
        for (int i = 0; i < 8; ++i) ss += rms_part[i * P_DIM + rowg];
        float rv = rsqrtf(ss * (1.0f / 512.0f) + 1e-6f);
#pragma unroll
        for (int nj = 0; nj < 4; ++nj) acc[mi][nj][r] *= rv;
      }
  }

#pragma unroll
  for (int mi = 0; mi < 2; ++mi)
#pragma unroll
    for (int nj = 0; nj < 4; ++nj){
      int col = n0 + nj * 16 + cb;
#pragma unroll
      for (int r = 0; r < 4; ++r){
        int rowg = m0 + w * 32 + mi * 16 + g * 4 + r;
        qkv_bf[(size_t)rowg * 1536 + col] = B16(acc[mi][nj][r]);
      }
    }
}

// ---------------- K3: MFMA neighborhood attention ---------------------------
#define KL_S 80
#define VT_S 232
#define PP_S 232
__global__ __launch_bounds__(256) void k_attn(const bf16* __restrict__ qkv_bfp,
                                              bf16* __restrict__ o_bf){
  __shared__ unsigned short kp[208 * KL_S];     // 33280 B (>= P 64*232=29696 B)
  __shared__ unsigned short vT[64 * VT_S];      // 29696 B
  const unsigned short* qkv = (const unsigned short*)qkv_bfp;

  int bid = blockIdx.x;            // 512 = 64 patches * 8 heads
  int head = bid & 7;
  int patch = bid >> 3;
  int t = patch >> 4;
  int ph = (patch >> 2) & 3, pw = patch & 3;
  int h0 = ph * 8, w0 = pw * 8;
  int rs = min(max(h0 - 3, 0), 18);
  int cs = min(max(w0 - 3, 0), 18);
  int tbase = t << 10;
  int tid = threadIdx.x;
  int cp = tid & 31, pxg = tid >> 5;

  for (int i = 0; i < 26; ++i){
    int px = i * 8 + pxg;
    unsigned val = 0;
    if (px < 196){
      int rr = px / 14, cc = px - rr * 14;
      size_t pn = (size_t)(tbase + (rs + rr) * 32 + (cs + cc));
      val = *(const unsigned*)&qkv[pn * 1536 + 512 + head * 64 + cp * 2];
    }
    *(unsigned*)&kp[px * KL_S + cp * 2] = val;
  }
  for (int i = 0; i < 14; ++i){
    int pp = i * 8 + pxg;
    int px0 = 2 * pp, px1 = px0 + 1;
    unsigned v0 = 0, v1 = 0;
    if (px0 < 196){
      int rr = px0 / 14, cc = px0 - rr * 14;
      size_t pn = (size_t)(tbase + (rs + rr) * 32 + (cs + cc));
      v0 = *(const unsigned*)&qkv[pn * 1536 + 1024 + head * 64 + cp * 2];
    }
    if (px1 < 196){
      int rr = px1 / 14, cc = px1 - rr * 14;
      size_t pn = (size_t)(tbase + (rs + rr) * 32 + (cs + cc));
      v1 = *(const unsigned*)&qkv[pn * 1536 + 1024 + head * 64 + cp * 2];
    }
    unsigned lo = (v0 & 0xffffu) | (v1 << 16);
    unsigned hi = (v0 >> 16) | (v1 & 0xffff0000u);
    *(unsigned*)&vT[(2 * cp) * VT_S + 2 * pp] = lo;
    *(unsigned*)&vT[(2 * cp + 1) * VT_S + 2 * pp] = hi;
  }

  int w = tid >> 6, l = tid & 63;
  int g = l >> 4, cb = l & 15;

  int q_a = w * 16 + cb;
  size_t abase = (size_t)(tbase + (h0 + (q_a >> 3)) * 32 + (w0 + (q_a & 7))) * 1536 + head * 64;
  short8 qa0 = *(const short8*)&qkv[abase + g * 8];
  short8 qa1 = *(const short8*)&qkv[abase + 32 + g * 8];

  __syncthreads();

  f32x4 acc[13];
#pragma unroll
  for (int nt = 0; nt < 13; ++nt)
#pragma unroll
    for (int r = 0; r < 4; ++r) acc[nt][r] = 0.f;
#pragma unroll
  for (int nt = 0; nt < 13; ++nt){
    short8 kb0 = *(const short8*)&kp[(nt * 16 + cb) * KL_S + g * 8];
    short8 kb1 = *(const short8*)&kp[(nt * 16 + cb) * KL_S + 32 + g * 8];
    acc[nt] = __builtin_amdgcn_mfma_f32_16x16x32_bf16(qa0, kb0, acc[nt], 0, 0, 0);
    acc[nt] = __builtin_amdgcn_mfma_f32_16x16x32_bf16(qa1, kb1, acc[nt], 0, 0, 0);
  }
  __syncthreads();

  int wr0[4], wc0[4];
#pragma unroll
  for (int r = 0; r < 4; ++r){
    int q_l = w * 16 + g * 4 + r;
    int hq = h0 + (q_l >> 3), wq = w0 + (q_l & 7);
    wr0[r] = min(max(hq - 3, 0), 25) - rs;
    wc0[r] = min(max(wq - 3, 0), 25) - cs;
  }
  float mx[4] = {-1e30f, -1e30f, -1e30f, -1e30f};
#pragma unroll
  for (int nt = 0; nt < 13; ++nt){
    int kg = nt * 16 + cb;
    int kr = kg / 14, kc = kg - kr * 14;
    bool kvalid = kg < 196;
#pragma unroll
    for (int r = 0; r < 4; ++r){
      bool v = kvalid && ((unsigned)(kr - wr0[r]) < 7u) && ((unsigned)(kc - wc0[r]) < 7u);
      float lg = v ? acc[nt][r] : -1e30f;
      acc[nt][r] = lg;
      mx[r] = fmaxf(mx[r], lg);
    }
  }
#pragma unroll
  for (int off = 1; off < 16; off <<= 1)
#pragma unroll
    for (int r = 0; r < 4; ++r) mx[r] = fmaxf(mx[r], __shfl_xor(mx[r], off, 64));
  float sm[4] = {0.f, 0.f, 0.f, 0.f};
#pragma unroll
  for (int nt = 0; nt < 13; ++nt)
#pragma unroll
    for (int r = 0; r < 4; ++r){
      float e = __expf(acc[nt][r] - mx[r]);
      acc[nt][r] = e;
      sm[r] += e;
    }
#pragma unroll
  for (int off = 1; off < 16; off <<= 1)
#pragma unroll
    for (int r = 0; r < 4; ++r) sm[r] += __shfl_xor(sm[r], off, 64);
  float inv[4];
#pragma unroll
  for (int r = 0; r < 4; ++r) inv[r] = 1.0f / sm[r];

#pragma unroll
  for (int nt = 0; nt < 13; ++nt)
#pragma unroll
    for (int r = 0; r < 4; ++r)
      *reinterpret_cast<bf16*>(&kp[(w * 16 + g * 4 + r) * PP_S + nt * 16 + cb]) = B16(acc[nt][r] * inv[r]);
#pragma unroll
  for (int r = 0; r < 4; ++r)
    kp[(w * 16 + g * 4 + r) * PP_S + 208 + cb] = 0;
  __syncthreads();

  f32x4 acc2[4];
#pragma unroll
  for (int ct = 0; ct < 4; ++ct)
#pragma unroll
    for (int r = 0; r < 4; ++r) acc2[ct][r] = 0.f;
#pragma unroll
  for (int kt = 0; kt < 7; ++kt){
    short8 pa = *(const short8*)&kp[(w * 16 + cb) * PP_S + kt * 32 + g * 8];
#pragma unroll
    for (int ct = 0; ct < 4; ++ct){
      short8 vb = *(const short8*)&vT[(ct * 16 + cb) * VT_S + kt * 32 + g * 8];
      acc2[ct] = __builtin_amdgcn_mfma_f32_16x16x32_bf16(pa, vb, acc2[ct], 0, 0, 0);
    }
  }
#pragma unroll
  for (int ct = 0; ct < 4; ++ct)
#pragma unroll
    for (int r = 0; r < 4; ++r){
      int q_l = w * 16 + g * 4 + r;
      int p = tbase + (h0 + (q_l >> 3)) * 32 + (w0 + (q_l & 7));
      o_bf[(size_t)p * 512 + head * 64 + ct * 16 + cb] = B16(acc2[ct][r]);
    }
}

// ---------------- K4: MFMA GEMM out (128x64, BK=64) + residual/transpose ----
__global__ __launch_bounds__(256) void k_gemm_out(const bf16* __restrict__ Ab,
                                                  const bf16* __restrict__ BTb,
                                                  const float* __restrict__ xres,
                                                  float* __restrict__ out){
  __shared__ unsigned short a_t[128 * AS];
  __shared__ unsigned short b_t[64 * AS];
  __shared__ float tile[64][65];
  const unsigned short* A  = (const unsigned short*)Ab;
  const unsigned short* BT = (const unsigned short*)BTb;
  int m0 = blockIdx.x * 128;   // pixels
  int n0 = blockIdx.y * 64;    // channels
  int tid = threadIdx.x;
  int w = tid >> 6, l = tid & 63, g = l >> 4, cb = l & 15;

  f32x4 acc[2][4];
#pragma unroll
  for (int mi = 0; mi < 2; ++mi)
#pragma unroll
    for (int nj = 0; nj < 4; ++nj)
#pragma unroll
      for (int r = 0; r < 4; ++r) acc[mi][nj][r] = 0.f;

  for (int kk = 0; kk < 512; kk += 64){
#pragma unroll
    for (int i = 0; i < 4; ++i){
      int sid = tid + i * 256;
      int row = sid >> 3, seg = sid & 7;
      *(uint4*)&a_t[row * AS + seg * 8] = *(const uint4*)&A[(size_t)(m0 + row) * 512 + kk + seg * 8];
    }
#pragma unroll
    for (int i = 0; i < 2; ++i){
      int sid = tid + i * 256;
      int row = sid >> 3, seg = sid & 7;
      *(uint4*)&b_t[row * AS + seg * 8] = *(const uint4*)&BT[(size_t)(n0 + row) * 512 + kk + seg * 8];
    }
    __syncthreads();
#pragma unroll
    for (int kc = 0; kc < 2; ++kc){
      short8 af[2];
#pragma unroll
      for (int mi = 0; mi < 2; ++mi)
        af[mi] = *(const short8*)&a_t[(w * 32 + mi * 16 + cb) * AS + kc * 32 + g * 8];
#pragma unroll
      for (int nj = 0; nj < 4; ++nj){
        short8 bfr = *(const short8*)&b_t[(nj * 16 + cb) * AS + kc * 32 + g * 8];
#pragma unroll
        for (int mi = 0; mi < 2; ++mi)
          acc[mi][nj] = __builtin_amdgcn_mfma_f32_16x16x32_bf16(af[mi], bfr, acc[mi][nj], 0, 0, 0);
      }
    }
    __syncthreads();
  }
  int grp = tid >> 6, lane = tid & 63;
#pragma unroll
  for (int hh = 0; hh < 2; ++hh){
    __syncthreads();
    if ((w >> 1) == hh){
#pragma unroll
      for (int mi = 0; mi < 2; ++mi)
#pragma unroll
        for (int nj = 0; nj < 4; ++nj)
#pragma unroll
          for (int r = 0; r < 4; ++r)
            tile[(w & 1) * 32 + mi * 16 + g * 4 + r][nj * 16 + cb] = acc[mi][nj][r];
    }
    __syncthreads();
    for (int j2 = grp; j2 < 64; j2 += 4){
      int c = n0 + j2;
      int p = m0 + hh * 64 + lane;
      out[(size_t)c * P_DIM + p] = tile[lane][j2] + xres[(size_t)c * P_DIM + p];
    }
  }
}

extern "C" void kernel_launch(void* const* d_in, const int* in_sizes, int n_in,
                              void* d_out, int out_size, void* d_ws, size_t ws_size,
                              hipStream_t stream){
  const float* x      = (const float*)d_in[0];
  const float* pos    = (const float*)d_in[1];
  const float* cond   = (const float*)d_in[2];
  const float* norm_w = (const float*)d_in[3];
  const float* qkv_w  = (const float*)d_in[4];
  const float* scale  = (const float*)d_in[5];
  const float* out_w  = (const float*)d_in[6];
  float* out = (float*)d_out;

  char* wp = (char*)d_ws;
  auto alloc = [&](size_t bytes) -> char* {
    char* r = wp;
    wp += (bytes + 255) & ~((size_t)255);
    return r;
  };
  float* rms_part = (float*)alloc(8 * 4096 * 4);
  bf16*  xt       = (bf16*) alloc((size_t)4096 * 512 * 2);
  bf16*  qkvT     = (bf16*) alloc((size_t)1536 * 512 * 2);
  bf16*  outT     = (bf16*) alloc((size_t)512 * 512 * 2);
  bf16*  qkv_bf   = (bf16*) alloc((size_t)4096 * 1536 * 2);
  bf16*  o_bf     = (bf16*) alloc((size_t)4096 * 512 * 2);

  k_pre     <<<1280,        256, 0, stream>>>(x, cond, norm_w, qkv_w, out_w,
                                              qkvT, outT, xt, rms_part);
  k_gemm_qkv<<<dim3(32,24), 256, 0, stream>>>(xt, qkvT, scale, pos, rms_part, qkv_bf);
  k_attn    <<<512,         256, 0, stream>>>(qkv_bf, o_bf);
  k_gemm_out<<<dim3(32,8),  256, 0, stream>>>(o_bf, outT, x, out);
}